// Round 19
// baseline (2246.740 us; speedup 1.0000x reference)
//
#include <hip/hip_runtime.h>
#include <hip/hip_bf16.h>

#define S_LEN 512
#define B_SZ  256
#define F_SZ  256
#define H_SZ  1024
#define BH    (B_SZ * H_SZ)
#define KEEP  0.5f

typedef float f32x4 __attribute__((ext_vector_type(4)));
typedef short s16x8 __attribute__((ext_vector_type(8)));
typedef int   i32x4 __attribute__((ext_vector_type(4)));

static __device__ __forceinline__ short f2bf(float f) {
    unsigned u = __builtin_bit_cast(unsigned, f);
    unsigned r = u + 0x7fffu + ((u >> 16) & 1u);   // RNE to bf16
    return (short)(r >> 16);
}

static __device__ __forceinline__ s16x8 pack8(f32x4 lo, f32x4 hi, float s) {
    s16x8 r;
#pragma unroll
    for (int i = 0; i < 4; ++i) { r[i] = f2bf(lo[i] * s); r[i + 4] = f2bf(hi[i] * s); }
    return r;
}

static __device__ __forceinline__ float fast_tanh(float v) {
    float e = __expf(2.0f * v);
    return (e - 1.0f) / (e + 1.0f);
}

#define SYS_LD(p)   __hip_atomic_load((p), __ATOMIC_RELAXED, __HIP_MEMORY_SCOPE_SYSTEM)
#define SYS_ST(p,v) __hip_atomic_store((p), (v), __ATOMIC_RELAXED, __HIP_MEMORY_SCOPE_SYSTEM)
#define AGT_LD(p)   __hip_atomic_load((p), __ATOMIC_RELAXED, __HIP_MEMORY_SCOPE_AGENT)

// Flag atomics (R14-proven): PURE -> no sc1 (XCD-local TCC); mixed -> sc0 sc1.
template<int PURE>
static __device__ __forceinline__ int rmw_flag(int* p, int v) {
    int r;
    if constexpr (PURE)
        asm volatile("global_atomic_add %0, %1, %2, off sc0\n\ts_waitcnt vmcnt(0)"
                     : "=v"(r) : "v"(p), "v"(v) : "memory");
    else
        asm volatile("global_atomic_add %0, %1, %2, off sc0 sc1\n\ts_waitcnt vmcnt(0)"
                     : "=v"(r) : "v"(p), "v"(v) : "memory");
    return r;
}

template<int PURE>
static __device__ __forceinline__ void sig_flag(int* p) {
    int one = 1;
    if constexpr (PURE)
        asm volatile("global_atomic_add %0, %1, off" :: "v"(p), "v"(one) : "memory");
    else
        asm volatile("global_atomic_add %0, %1, off sc1" :: "v"(p), "v"(one) : "memory");
}

template<int PURE>
static __device__ __forceinline__ void sth(short* p, short v) {
    int vi = v;
    if constexpr (PURE)
        asm volatile("global_store_short %0, %1, off" :: "v"(p), "v"(vi) : "memory");
    else
        asm volatile("global_store_short %0, %1, off sc0 sc1" :: "v"(p), "v"(vi) : "memory");
}

#define MFMA(A, B, C) __builtin_amdgcn_mfma_f32_16x16x32_bf16((A), (B), (C), 0, 0, 0)

// R14-frozen chain + in-loop x prefetch (replaces the xi pre-pass kernel):
// raw x(s+1) is loaded into xraw[16] registers right AFTER the signal (16
// independent plain loads, compiler-managed waits -> spill-safe); the HBM
// latency drains inside the next spin's vmcnt(0). The pack+8 input-proj
// MFMAs execute after the 16 stage loads are issued, inside the stage-
// latency shadow.
template<int PURE>
static __device__ __forceinline__ void step_loop(
    const float* __restrict__ x, const float* __restrict__ h0,
    float* __restrict__ out, short* __restrict__ hbuf, int* __restrict__ flags,
    char* h_lds, const s16x8 (&wh)[32], const s16x8 (&wif)[8], float bj,
    int g, int b0, int role, int j, int wIdx, int wave, int lane, int tid, int dmask)
{
    const int ln = lane & 15;
    const int lk = lane >> 4;
    const int arow = b0 + ln;
    const int crow = b0 + lk * 4;
    const int xr = (ln & 7) << 4;                 // read-side LDS swizzle
    const int rbase = ln * 2048 + lk * 16;        // A-frag base byte in h_lds
    int* const inbox  = flags + role * 64;        // my WG's 64 counters
    int* const fanout = flags + ((g * 16 + lane) * 64 + wIdx);  // lanes 0-15

    // prologue: raw x(0)
    f32x4 xraw[16];
    {
        const float* xp = x + (size_t)arow * F_SZ + lk * 8;
#pragma unroll
        for (int kf = 0; kf < 8; ++kf) {
            xraw[2 * kf]     = *(const f32x4*)(xp + kf * 32);
            xraw[2 * kf + 1] = *(const f32x4*)(xp + kf * 32 + 4);
        }
    }

#pragma unroll 1
    for (int s = 0; s < S_LEN; ++s) {
        f32x4 acc[4];
        acc[0] = f32x4{ bj, bj, bj, bj };
        acc[1] = f32x4{ 0.f, 0.f, 0.f, 0.f };
        acc[2] = f32x4{ 0.f, 0.f, 0.f, 0.f };
        acc[3] = f32x4{ 0.f, 0.f, 0.f, 0.f };

        if (s > 0) {
            // ---- wave0: atomic RMW poll on own inbox (R14-proven) ----
            if (wave == 0) {
                int it = 0;
                for (;;) {
                    int v = rmw_flag<PURE>(inbox + lane, 0);
                    if (__all(v >= s)) break;
                    if (++it > (1 << 14)) break;    // watchdog: fail-visible
                    __builtin_amdgcn_s_sleep(1);
                }
            }
            __syncthreads();   // release waves 1-3; orders poll before loads

            // ---- issue 32KB h stage loads (16 x 8B per thread) ----
            const char* slice = (const char*)(hbuf + (size_t)((s - 1) & dmask) * BH
                                              + (size_t)b0 * H_SZ);
            long o[16];
#pragma unroll
            for (int r = 0; r < 16; ++r) {
                const long* p = (const long*)(slice + r * 2048) + tid;
                o[r] = PURE ? AGT_LD(p) : SYS_LD(p);
            }

            // ---- input-proj MFMAs from prefetched xraw (stage-latency shadow) ----
#pragma unroll
            for (int kf = 0; kf < 8; ++kf) {
                s16x8 a = pack8(xraw[2 * kf], xraw[2 * kf + 1], 1.0f);
                acc[kf & 1] = MFMA(a, wif[kf], acc[kf & 1]);
            }

            // ---- swizzled LDS image + barrier ----
#pragma unroll
            for (int r = 0; r < 16; ++r)
                *(long*)(h_lds + ((r * 2048 + tid * 8) ^ ((r & 7) << 4))) = o[r];
            __syncthreads();

            // ---- 32 h-MFMAs from swizzled LDS, 4 independent chains ----
#pragma unroll
            for (int ks = 0; ks < 32; ++ks) {
                s16x8 a = *(const s16x8*)(h_lds + ((rbase + ks * 64) ^ xr));
                acc[ks & 3] = MFMA(a, wh[ks], acc[ks & 3]);
            }
        } else {
            // step 0: input proj + h0 broadcast (same fragment for all rows)
#pragma unroll
            for (int kf = 0; kf < 8; ++kf) {
                s16x8 a = pack8(xraw[2 * kf], xraw[2 * kf + 1], 1.0f);
                acc[kf & 1] = MFMA(a, wif[kf], acc[kf & 1]);
            }
#pragma unroll
            for (int ks = 0; ks < 32; ++ks) {
                const float* p = h0 + ks * 32 + lk * 8;
                s16x8 a = pack8(*(const f32x4*)p, *(const f32x4*)(p + 4), KEEP);
                acc[ks & 3] = MFMA(a, wh[ks], acc[ks & 3]);
            }
        }

        f32x4 r4 = (acc[0] + acc[1]) + (acc[2] + acc[3]);

        // C/D layout: col = lane&15 (=j), row = (lane>>4)*4 + r (=batch)
        if (s < S_LEN - 1) {
            short* op = hbuf + (size_t)(s & dmask) * BH;
#pragma unroll
            for (int r = 0; r < 4; ++r)
                sth<PURE>(op + (crow + r) * H_SZ + j, f2bf(KEEP * fast_tanh(r4[r])));
            asm volatile("s_waitcnt vmcnt(0)" ::: "memory");  // h at L2/L3 first
            if (lane < 16) sig_flag<PURE>(fanout);  // signal 16 group inboxes

            // ---- prefetch raw x(s+1): independent loads, drained by the next
            //      spin's vmcnt(0); "memory"-clobbered asm pins them here ----
            const float* xp = x + ((size_t)(s + 1) * B_SZ + arow) * F_SZ + lk * 8;
#pragma unroll
            for (int kf = 0; kf < 8; ++kf) {
                xraw[2 * kf]     = *(const f32x4*)(xp + kf * 32);
                xraw[2 * kf + 1] = *(const f32x4*)(xp + kf * 32 + 4);
            }
        } else {
#pragma unroll
            for (int r = 0; r < 4; ++r)
                out[(crow + r) * H_SZ + j] = fast_tanh(r4[r]);
        }
    }
}

// Grid: 256 WGs x 256 thr. role remap clusters each 16-WG group onto one XCD
// (verified at runtime via HW_REG_XCC_ID roster; fallback = fabric-scope ops).
__global__ __launch_bounds__(256, 1) void rnn_fused(
    const float* __restrict__ x, const float* __restrict__ Wi,
    const float* __restrict__ bias, const float* __restrict__ Wh,
    const float* __restrict__ h0, float* __restrict__ out,
    short* __restrict__ hbuf, int* __restrict__ roster, int* __restrict__ flags,
    int dmask)
{
    __shared__ char h_lds[32768];   // 16 rows x 1024 bf16, XOR-swizzled image
    __shared__ int sh_pure;
    const int bid  = blockIdx.x;
    const int role = ((bid & 7) << 5) | (bid >> 3);   // same-XCD groups under RR lore
    const int g    = role >> 4;
    const int t    = role & 15;
    const int tid  = threadIdx.x;
    const int wave = tid >> 6;
    const int lane = tid & 63;
    const int ln   = lane & 15;
    const int lk   = lane >> 4;

    int xcc;
    asm volatile("s_getreg_b32 %0, hwreg(HW_REG_XCC_ID)" : "=s"(xcc));
    xcc &= 7;

    if (tid == 0) SYS_ST(&roster[role], xcc + 1);     // publish my XCD (one-time)
    if (tid < 16) {                                   // verify group co-residency
        const int* rp = roster + g * 16 + tid;
        int v, it = 0;
        do { v = SYS_LD(rp); if (v) break; if (++it > (1 << 18)) break;
             __builtin_amdgcn_s_sleep(1); } while (1);
        int p = __all(v == __shfl(v, 0));
        if (tid == 0) sh_pure = p;
    }
    __syncthreads();
    const int pure = sh_pure;

    const int b0 = g * 16;
    const int j  = t * 64 + wave * 16 + ln;
    const int wIdx = t * 4 + wave;

    // --- W_h2h / W_i2h j-slices live in registers as MFMA B-fragments ---
    s16x8 wh[32];
#pragma unroll
    for (int ks = 0; ks < 32; ++ks) {
        const float* p = Wh + (size_t)j * H_SZ + ks * 32 + lk * 8;
        wh[ks] = pack8(*(const f32x4*)p, *(const f32x4*)(p + 4), 1.0f);
    }
    s16x8 wif[8];
#pragma unroll
    for (int kf = 0; kf < 8; ++kf) {
        const float* p = Wi + (size_t)j * F_SZ + kf * 32 + lk * 8;
        wif[kf] = pack8(*(const f32x4*)p, *(const f32x4*)(p + 4), 1.0f);
    }
    const float bj = bias[j];

    if (pure)
        step_loop<1>(x, h0, out, hbuf, flags, h_lds, wh, wif, bj,
                     g, b0, role, j, wIdx, wave, lane, tid, dmask);
    else
        step_loop<0>(x, h0, out, hbuf, flags, h_lds, wh, wif, bj,
                     g, b0, role, j, wIdx, wave, lane, tid, dmask);
}

extern "C" void kernel_launch(void* const* d_in, const int* in_sizes, int n_in,
                              void* d_out, int out_size, void* d_ws, size_t ws_size,
                              hipStream_t stream) {
    const float* x  = (const float*)d_in[0];
    const float* Wi = (const float*)d_in[1];
    const float* bi = (const float*)d_in[2];
    const float* Wh = (const float*)d_in[3];
    const float* h0 = (const float*)d_in[4];
    float* out = (float*)d_out;

    int*   roster = (int*)d_ws;                          // 256 ints @ 0
    int*   flags  = (int*)((char*)d_ws + (4 << 10));     // 256 inboxes x 64 = 64KB
    short* hbuf   = (short*)((char*)d_ws + (128 << 10)); // depth x 512 KB bf16

    const size_t need4 = (128u << 10) + 4 * (size_t)BH * 2;   // ~2.1 MB
    const int dmask = (ws_size >= need4) ? 3 : 1;

    // roster + inboxes MUST be zero every call (graph replays don't re-poison)
    (void)hipMemsetAsync(d_ws, 0, (68 << 10), stream);

    rnn_fused<<<dim3(256), dim3(256), 0, stream>>>(
        x, Wi, bi, Wh, h0, out, hbuf, roster, flags, dmask);
}

// Round 20
// 1582.431 us; speedup vs baseline: 1.4198x; 1.4198x over previous
//
#include <hip/hip_runtime.h>
#include <hip/hip_bf16.h>

#define S_LEN 512
#define B_SZ  256
#define F_SZ  256
#define H_SZ  1024
#define BH    (B_SZ * H_SZ)
#define KEEP  0.5f

typedef float f32x4 __attribute__((ext_vector_type(4)));
typedef short s16x8 __attribute__((ext_vector_type(8)));
typedef int   i32x4 __attribute__((ext_vector_type(4)));

static __device__ __forceinline__ short f2bf(float f) {
    unsigned u = __builtin_bit_cast(unsigned, f);
    unsigned r = u + 0x7fffu + ((u >> 16) & 1u);   // RNE to bf16
    return (short)(r >> 16);
}

static __device__ __forceinline__ s16x8 pack8(f32x4 lo, f32x4 hi, float s) {
    s16x8 r;
#pragma unroll
    for (int i = 0; i < 4; ++i) { r[i] = f2bf(lo[i] * s); r[i + 4] = f2bf(hi[i] * s); }
    return r;
}

// packed converts (xi_gemm only — isolated kernel)
static __device__ __forceinline__ s16x8 pack8_pk(f32x4 lo, f32x4 hi) {
    int w0, w1, w2, w3;
    asm("v_cvt_pk_bf16_f32 %0, %1, %2" : "=v"(w0) : "v"(lo[0]), "v"(lo[1]));
    asm("v_cvt_pk_bf16_f32 %0, %1, %2" : "=v"(w1) : "v"(lo[2]), "v"(lo[3]));
    asm("v_cvt_pk_bf16_f32 %0, %1, %2" : "=v"(w2) : "v"(hi[0]), "v"(hi[1]));
    asm("v_cvt_pk_bf16_f32 %0, %1, %2" : "=v"(w3) : "v"(hi[2]), "v"(hi[3]));
    i32x4 r = { w0, w1, w2, w3 };
    return __builtin_bit_cast(s16x8, r);
}

static __device__ __forceinline__ long pack4_pk(f32x4 a) {
    int lo, hi;
    asm("v_cvt_pk_bf16_f32 %0, %1, %2" : "=v"(lo) : "v"(a[0]), "v"(a[1]));
    asm("v_cvt_pk_bf16_f32 %0, %1, %2" : "=v"(hi) : "v"(a[2]), "v"(a[3]));
    return (long)(((unsigned long)(unsigned)hi << 32) | (unsigned)lo);
}

static __device__ __forceinline__ f32x4 unpack4(long v) {
    unsigned lo = (unsigned)v, hi = (unsigned)((unsigned long)v >> 32);
    f32x4 r;
    r[0] = __builtin_bit_cast(float, lo << 16);
    r[1] = __builtin_bit_cast(float, lo & 0xffff0000u);
    r[2] = __builtin_bit_cast(float, hi << 16);
    r[3] = __builtin_bit_cast(float, hi & 0xffff0000u);
    return r;
}

static __device__ __forceinline__ float fast_tanh(float v) {
    float e = __expf(2.0f * v);
    return (e - 1.0f) / (e + 1.0f);
}

#define SYS_LD(p)   __hip_atomic_load((p), __ATOMIC_RELAXED, __HIP_MEMORY_SCOPE_SYSTEM)
#define SYS_ST(p,v) __hip_atomic_store((p), (v), __ATOMIC_RELAXED, __HIP_MEMORY_SCOPE_SYSTEM)
#define AGT_LD(p)   __hip_atomic_load((p), __ATOMIC_RELAXED, __HIP_MEMORY_SCOPE_AGENT)

// Flag atomics (R14-proven): PURE -> no sc1 (XCD-local TCC); mixed -> sc0 sc1.
template<int PURE>
static __device__ __forceinline__ int rmw_flag(int* p, int v) {
    int r;
    if constexpr (PURE)
        asm volatile("global_atomic_add %0, %1, %2, off sc0\n\ts_waitcnt vmcnt(0)"
                     : "=v"(r) : "v"(p), "v"(v) : "memory");
    else
        asm volatile("global_atomic_add %0, %1, %2, off sc0 sc1\n\ts_waitcnt vmcnt(0)"
                     : "=v"(r) : "v"(p), "v"(v) : "memory");
    return r;
}

template<int PURE>
static __device__ __forceinline__ void sig_flag(int* p) {
    int one = 1;
    if constexpr (PURE)
        asm volatile("global_atomic_add %0, %1, off" :: "v"(p), "v"(one) : "memory");
    else
        asm volatile("global_atomic_add %0, %1, off sc1" :: "v"(p), "v"(one) : "memory");
}

template<int PURE>
static __device__ __forceinline__ void sth(short* p, short v) {
    int vi = v;
    if constexpr (PURE)
        asm volatile("global_store_short %0, %1, off" :: "v"(p), "v"(vi) : "memory");
    else
        asm volatile("global_store_short %0, %1, off sc0 sc1" :: "v"(p), "v"(vi) : "memory");
}

#define MFMA(A, B, C) __builtin_amdgcn_mfma_f32_16x16x32_bf16((A), (B), (C), 0, 0, 0)

// Hot recurrence — R14 structure byte-for-byte; sole delta: poll has no
// s_sleep (each probe is already a ~400-600cy coherent atomic RMW; the sleep
// only coarsened detection). Watchdog retained: fail-visible, never hangs.
template<int PURE, int XI>
static __device__ __forceinline__ void step_loop(
    const float* __restrict__ x, const float* __restrict__ h0,
    float* __restrict__ out, short* __restrict__ hbuf, int* __restrict__ flags,
    const char* __restrict__ xi_lane, char* h_lds,
    const s16x8 (&wh)[32], const s16x8 (&wif)[8], float bj,
    int g, int b0, int role, int j, int wIdx, int wave, int lane, int tid, int dmask)
{
    const int ln = lane & 15;
    const int lk = lane >> 4;
    const int arow = b0 + ln;
    const int crow = b0 + lk * 4;
    const int xr = (ln & 7) << 4;                 // read-side LDS swizzle
    const int rbase = ln * 2048 + lk * 16;        // A-frag base byte in h_lds
    int* const inbox  = flags + role * 64;        // my WG's 64 counters
    int* const fanout = flags + ((g * 16 + lane) * 64 + wIdx);  // lanes 0-15

    long xv = 0;
    if constexpr (XI) xv = *(const long*)xi_lane; // s=0 prefetch

#pragma unroll 1
    for (int s = 0; s < S_LEN; ++s) {
        f32x4 acc[4];
        acc[1] = f32x4{ 0.f, 0.f, 0.f, 0.f };
        acc[2] = f32x4{ 0.f, 0.f, 0.f, 0.f };
        acc[3] = f32x4{ 0.f, 0.f, 0.f, 0.f };

        if constexpr (!XI) {
            acc[0] = f32x4{ bj, bj, bj, bj };
            const float* xp = x + ((size_t)s * B_SZ + arow) * F_SZ + lk * 8;
#pragma unroll
            for (int kf = 0; kf < 8; ++kf) {
                s16x8 a = pack8(*(const f32x4*)(xp + kf * 32),
                                *(const f32x4*)(xp + kf * 32 + 4), 1.0f);
                acc[kf & 1] = MFMA(a, wif[kf], acc[kf & 1]);
            }
        }

        if (s > 0) {
            // ---- wave0: atomic RMW poll on own inbox (coherent every iter) ----
            if (wave == 0) {
                int it = 0;
                for (;;) {
                    int v = rmw_flag<PURE>(inbox + lane, 0);
                    if (__all(v >= s)) break;
                    if (++it > (1 << 15)) break;    // watchdog: fail-visible
                }
            }
            __syncthreads();   // release waves 1-3; orders poll before loads

            // ---- stage 32KB h slice -> LDS (R11-proven path) ----
            const char* slice = (const char*)(hbuf + (size_t)((s - 1) & dmask) * BH
                                              + (size_t)b0 * H_SZ);
            long o[16];
#pragma unroll
            for (int r = 0; r < 16; ++r) {
                const long* p = (const long*)(slice + r * 2048) + tid;
                o[r] = PURE ? AGT_LD(p) : SYS_LD(p);
            }
#pragma unroll
            for (int r = 0; r < 16; ++r)
                *(long*)(h_lds + ((r * 2048 + tid * 8) ^ ((r & 7) << 4))) = o[r];
            __syncthreads();
            if constexpr (XI) acc[0] = unpack4(xv);

            // ---- 32 h-MFMAs from swizzled LDS, 4 independent chains ----
#pragma unroll
            for (int ks = 0; ks < 32; ++ks) {
                s16x8 a = *(const s16x8*)(h_lds + ((rbase + ks * 64) ^ xr));
                acc[ks & 3] = MFMA(a, wh[ks], acc[ks & 3]);
            }
        } else {
            if constexpr (XI) acc[0] = unpack4(xv);
            // step 0: h0 broadcast across batch (same fragment for all rows)
#pragma unroll
            for (int ks = 0; ks < 32; ++ks) {
                const float* p = h0 + ks * 32 + lk * 8;
                s16x8 a = pack8(*(const f32x4*)p, *(const f32x4*)(p + 4), KEEP);
                acc[ks & 3] = MFMA(a, wh[ks], acc[ks & 3]);
            }
        }

        f32x4 r4 = (acc[0] + acc[1]) + (acc[2] + acc[3]);

        // C/D layout: col = lane&15 (=j), row = (lane>>4)*4 + r (=batch)
        if (s < S_LEN - 1) {
            short* op = hbuf + (size_t)(s & dmask) * BH;
#pragma unroll
            for (int r = 0; r < 4; ++r)
                sth<PURE>(op + (crow + r) * H_SZ + j, f2bf(KEEP * fast_tanh(r4[r])));
            asm volatile("s_waitcnt vmcnt(0)" ::: "memory");  // h at L2/L3 first
            if (lane < 16) sig_flag<PURE>(fanout);  // signal 16 group inboxes
            // prefetch next step's xi: HBM latency hides in the next wait
            if constexpr (XI)
                xv = *(const long*)(xi_lane + (size_t)(s + 1) * (256u * 4 * 64 * 8));
        } else {
#pragma unroll
            for (int r = 0; r < 4; ++r)
                out[(crow + r) * H_SZ + j] = fast_tanh(r4[r]);
        }
    }
}

// ---------- kernel A: xi = x@Wi^T + b (sync-free; coalesced output) ----------
// Output layout: [S][role(256)][wave(4)][lane(64)] x 8B (4 bf16 batch rows).
// Grid 1024 = 256 roles x 4 s-chunks (128 steps each): Wi-fragment preamble
// amortized over 2x the work vs R14's grid 2048.
__global__ __launch_bounds__(256, 1) void xi_gemm(
    const float* __restrict__ x, const float* __restrict__ Wi,
    const float* __restrict__ bias, char* __restrict__ xi)
{
    const int bid  = blockIdx.x;
    const int role = bid & 255;
    const int c    = bid >> 8;          // s-chunk (128 steps), 0..3
    const int tid  = threadIdx.x;
    const int wave = tid >> 6;
    const int lane = tid & 63;
    const int ln   = lane & 15;
    const int lk   = lane >> 4;

    const int b0    = (role >> 4) * 16;
    const int jtile = (role & 15) * 64;

    s16x8 wia[4][8];
    float b4[4];
#pragma unroll
    for (int jt = 0; jt < 4; ++jt) {
        b4[jt] = bias[jtile + jt * 16 + ln];
#pragma unroll
        for (int kf = 0; kf < 8; ++kf) {
            const float* p = Wi + (size_t)(jtile + jt * 16 + ln) * F_SZ
                           + kf * 32 + lk * 8;
            wia[jt][kf] = pack8_pk(*(const f32x4*)p, *(const f32x4*)(p + 4));
        }
    }

#pragma unroll 1
    for (int i = 0; i < 32; ++i) {
        const int s = c * 128 + wave + 4 * i;
        const float* xp = x + ((size_t)s * B_SZ + b0 + ln) * F_SZ + lk * 8;
        s16x8 af[8];
#pragma unroll
        for (int kf = 0; kf < 8; ++kf)
            af[kf] = pack8_pk(*(const f32x4*)(xp + kf * 32),
                              *(const f32x4*)(xp + kf * 32 + 4));
#pragma unroll
        for (int jt = 0; jt < 4; ++jt) {
            f32x4 a = { b4[jt], b4[jt], b4[jt], b4[jt] };
#pragma unroll
            for (int kf = 0; kf < 8; ++kf)
                a = MFMA(af[kf], wia[jt][kf], a);
            // producer lane l holds exactly consumer (role, wave=jt, lane=l)'s 8B
            *(long*)(xi + ((((size_t)s * 256 + role) * 4 + jt) * 64 + lane) * 8)
                = pack4_pk(a);
        }
    }
}

// ---------- kernel B: recurrence (R14-exact protocol) ----------
template<int XI>
__global__ __launch_bounds__(256, 1) void rnn_fused(
    const float* __restrict__ x, const float* __restrict__ Wi,
    const float* __restrict__ bias, const float* __restrict__ Wh,
    const float* __restrict__ h0, float* __restrict__ out,
    short* __restrict__ hbuf, int* __restrict__ roster, int* __restrict__ flags,
    const char* __restrict__ xi, int dmask)
{
    __shared__ char h_lds[32768];   // 16 rows x 1024 bf16, XOR-swizzled image
    __shared__ int sh_pure;
    const int bid  = blockIdx.x;
    const int role = ((bid & 7) << 5) | (bid >> 3);   // same-XCD groups under RR lore
    const int g    = role >> 4;
    const int t    = role & 15;
    const int tid  = threadIdx.x;
    const int wave = tid >> 6;
    const int lane = tid & 63;
    const int ln   = lane & 15;
    const int lk   = lane >> 4;

    int xcc;
    asm volatile("s_getreg_b32 %0, hwreg(HW_REG_XCC_ID)" : "=s"(xcc));
    xcc &= 7;

    if (tid == 0) SYS_ST(&roster[role], xcc + 1);     // publish my XCD (one-time)
    if (tid < 16) {                                   // verify group co-residency
        const int* rp = roster + g * 16 + tid;
        int v, it = 0;
        do { v = SYS_LD(rp); if (v) break; if (++it > (1 << 18)) break;
             __builtin_amdgcn_s_sleep(1); } while (1);
        int p = __all(v == __shfl(v, 0));
        if (tid == 0) sh_pure = p;
    }
    __syncthreads();
    const int pure = sh_pure;

    const int b0 = g * 16;
    const int j  = t * 64 + wave * 16 + ln;
    const int wIdx = t * 4 + wave;
    const char* xi_lane = xi + (((size_t)role * 4 + wave) * 64 + lane) * 8;

    s16x8 wh[32];
#pragma unroll
    for (int ks = 0; ks < 32; ++ks) {
        const float* p = Wh + (size_t)j * H_SZ + ks * 32 + lk * 8;
        wh[ks] = pack8(*(const f32x4*)p, *(const f32x4*)(p + 4), 1.0f);
    }
    s16x8 wif[8];
    if constexpr (!XI) {
#pragma unroll
        for (int kf = 0; kf < 8; ++kf) {
            const float* p = Wi + (size_t)j * F_SZ + kf * 32 + lk * 8;
            wif[kf] = pack8(*(const f32x4*)p, *(const f32x4*)(p + 4), 1.0f);
        }
    } else {
#pragma unroll
        for (int kf = 0; kf < 8; ++kf) wif[kf] = s16x8{0,0,0,0,0,0,0,0};
    }
    const float bj = XI ? 0.f : bias[j];

    if (pure)
        step_loop<1, XI>(x, h0, out, hbuf, flags, xi_lane, h_lds, wh, wif, bj,
                         g, b0, role, j, wIdx, wave, lane, tid, dmask);
    else
        step_loop<0, XI>(x, h0, out, hbuf, flags, xi_lane, h_lds, wh, wif, bj,
                         g, b0, role, j, wIdx, wave, lane, tid, dmask);
}

extern "C" void kernel_launch(void* const* d_in, const int* in_sizes, int n_in,
                              void* d_out, int out_size, void* d_ws, size_t ws_size,
                              hipStream_t stream) {
    const float* x  = (const float*)d_in[0];
    const float* Wi = (const float*)d_in[1];
    const float* bi = (const float*)d_in[2];
    const float* Wh = (const float*)d_in[3];
    const float* h0 = (const float*)d_in[4];
    float* out = (float*)d_out;

    int*   roster = (int*)d_ws;                          // 256 ints @ 0
    int*   flags  = (int*)((char*)d_ws + (4 << 10));     // 256 inboxes x 64 = 64KB
    short* hbuf   = (short*)((char*)d_ws + (128 << 10)); // depth x 512 KB bf16
    char*  xi     = (char*)d_ws + (128 << 10) + 4 * (size_t)BH * 2;

    const size_t need4   = (128u << 10) + 4 * (size_t)BH * 2;          // ~2.1 MB
    const size_t need_xi = need4 + (size_t)S_LEN * 256 * 4 * 64 * 8;   // ~270.7 MB

    const int dmask = (ws_size >= need4) ? 3 : 1;

    // roster + inboxes MUST be zero every call (graph replays don't re-poison)
    (void)hipMemsetAsync(d_ws, 0, (68 << 10), stream);

    if (ws_size >= need_xi) {
        xi_gemm<<<dim3(1024), dim3(256), 0, stream>>>(x, Wi, bi, xi);
        rnn_fused<1><<<dim3(256), dim3(256), 0, stream>>>(
            x, Wi, bi, Wh, h0, out, hbuf, roster, flags, xi, dmask);
    } else {
        rnn_fused<0><<<dim3(256), dim3(256), 0, stream>>>(
            x, Wi, bi, Wh, h0, out, hbuf, roster, flags, nullptr, dmask);
    }
}